// Round 2
// baseline (203.670 us; speedup 1.0000x reference)
//
#include <hip/hip_runtime.h>
#include <math.h>

#define H1 1024
#define H2 512
#define NB_P1 640               // phase-1 blocks: 2560 waves (1024 h1 + 1536 gh2 jobs)
#define NB_P2 128               // phase-2 blocks: 512 waves (h2 jobs)
#define NBLK (NB_P1 + NB_P2)    // 768 <= 1024 co-resident capacity at 4 blocks/CU

__device__ __forceinline__ float sigmoidf_(float x) { return 1.0f / (1.0f + __expf(-x)); }
__device__ __forceinline__ float dot4(float4 a, float4 b) {
    return a.x * b.x + a.y * b.y + a.z * b.z + a.w * b.w;
}
__device__ __forceinline__ float wave_sum(float v) {
#pragma unroll
    for (int o = 32; o; o >>= 1) v += __shfl_xor(v, o, 64);
    return v;
}

__global__ __launch_bounds__(256, 4) void gru_fused(
    const int* __restrict__ ids,
    const float* __restrict__ h1_in,
    const float* __restrict__ h2_in,
    const float* __restrict__ emb,
    const float* __restrict__ w_ih1,
    const float* __restrict__ w_hh1,
    const float* __restrict__ b_ih1,
    const float* __restrict__ b_hh1,
    const float* __restrict__ w_ih2,
    const float* __restrict__ w_hh2,
    const float* __restrict__ b_ih2,
    const float* __restrict__ b_hh2,
    float* __restrict__ d_out,
    unsigned int* __restrict__ cnt,   // cnt[0]: h1-done count, cnt[1]: gh2-done count
    float* __restrict__ gh2_ws)
{
    const int lane = threadIdx.x & 63;
    const int wid  = threadIdx.x >> 6;
    const int b    = blockIdx.x;

    if (b < NB_P1) {
        const int w = b * 4 + wid;          // [0, 2560)
        if (w < H1) {
            // ---- h1[j]: 6 dots of length 1024, one wave ----
            const int j = w;
            const float* xrow = emb + (size_t)ids[0] * H1;
            float acc[6] = {0, 0, 0, 0, 0, 0};
#pragma unroll
            for (int k = 0; k < 4; ++k) {
                const int idx = lane + 64 * k;              // float4 index, 256 total
                const float4 x4 = ((const float4*)xrow)[idx];
                const float4 h4 = ((const float4*)h1_in)[idx];
#pragma unroll
                for (int g = 0; g < 3; ++g) {
                    const float4 a = ((const float4*)(w_ih1 + (size_t)(g * H1 + j) * H1))[idx];
                    const float4 c = ((const float4*)(w_hh1 + (size_t)(g * H1 + j) * H1))[idx];
                    acc[g]     += dot4(x4, a);
                    acc[3 + g] += dot4(h4, c);
                }
            }
#pragma unroll
            for (int g = 0; g < 6; ++g) acc[g] = wave_sum(acc[g]);
            if (lane == 0) {
                const float xr = acc[0] + b_ih1[j];
                const float xz = acc[1] + b_ih1[j + H1];
                const float xn = acc[2] + b_ih1[j + 2 * H1];
                const float hr = acc[3] + b_hh1[j];
                const float hz = acc[4] + b_hh1[j + H1];
                const float hn = acc[5] + b_hh1[j + 2 * H1];
                const float r = sigmoidf_(xr + hr);
                const float z = sigmoidf_(xz + hz);
                const float n = tanhf(xn + r * hn);
                d_out[H2 + j] = (1.0f - z) * n + z * h1_in[j];   // h1 at flat offset 512
                __threadfence();                                  // agent release
                atomicAdd(&cnt[0], 1u);                           // device-scope
            }
        } else {
            // ---- gh2[row] = h2_in . w_hh2[row] + b_hh2[row], one wave ----
            const int row = w - H1;             // [0, 1536)
            float acc = 0.0f;
#pragma unroll
            for (int k = 0; k < 2; ++k) {
                const int idx = lane + 64 * k;                  // 128 float4 total
                const float4 h4 = ((const float4*)h2_in)[idx];
                const float4 wv = ((const float4*)(w_hh2 + (size_t)row * H2))[idx];
                acc += dot4(h4, wv);
            }
            acc = wave_sum(acc);
            if (lane == 0) {
                gh2_ws[row] = acc + b_hh2[row];
                __threadfence();
                atomicAdd(&cnt[1], 1u);
            }
        }
    } else {
        // ---- phase 2: h2[j], one wave; preload w_ih2 rows BEFORE spinning ----
        const int j = (b - NB_P1) * 4 + wid;    // [0, 512)
        float4 wa[3][4];
#pragma unroll
        for (int g = 0; g < 3; ++g)
#pragma unroll
            for (int k = 0; k < 4; ++k)
                wa[g][k] = ((const float4*)(w_ih2 + (size_t)(g * H2 + j) * H1))[lane + 64 * k];
        const float bxr = b_ih2[j], bxz = b_ih2[j + H2], bxn = b_ih2[j + 2 * H2];
        const float hprev = h2_in[j];
        __builtin_amdgcn_sched_barrier(0);      // keep preloads issued before the spin
        while (__hip_atomic_load(&cnt[0], __ATOMIC_ACQUIRE, __HIP_MEMORY_SCOPE_AGENT) < (unsigned)H1 ||
               __hip_atomic_load(&cnt[1], __ATOMIC_ACQUIRE, __HIP_MEMORY_SCOPE_AGENT) < 1536u)
            __builtin_amdgcn_s_sleep(2);
        __builtin_amdgcn_sched_barrier(0);      // keep h1 loads after the acquire
        const float* h1v = d_out + H2;
        float acc3[3] = {0, 0, 0};
#pragma unroll
        for (int k = 0; k < 4; ++k) {
            const float4 hh = ((const float4*)h1v)[lane + 64 * k];
#pragma unroll
            for (int g = 0; g < 3; ++g) acc3[g] += dot4(hh, wa[g][k]);
        }
#pragma unroll
        for (int g = 0; g < 3; ++g) acc3[g] = wave_sum(acc3[g]);
        const float gv = (lane < 3) ? gh2_ws[j + H2 * lane] : 0.0f;
        const float hr = __shfl(gv, 0, 64);
        const float hz = __shfl(gv, 1, 64);
        const float hn = __shfl(gv, 2, 64);
        if (lane == 0) {
            const float r = sigmoidf_(acc3[0] + bxr + hr);
            const float z = sigmoidf_(acc3[1] + bxz + hz);
            const float n = tanhf(acc3[2] + bxn + r * hn);
            const float h = (1.0f - z) * n + z * hprev;
            d_out[j] = h;                // output (== h2)
            d_out[3 * H2 + j] = h;       // h2 at flat offset 1536
        }
    }
}

extern "C" void kernel_launch(void* const* d_in, const int* in_sizes, int n_in,
                              void* d_out, int out_size, void* d_ws, size_t ws_size,
                              hipStream_t stream) {
    const int*   ids   = (const int*)d_in[0];
    const float* h1_in = (const float*)d_in[1];
    const float* h2_in = (const float*)d_in[2];
    const float* emb   = (const float*)d_in[3];
    const float* w_ih1 = (const float*)d_in[4];
    const float* w_hh1 = (const float*)d_in[5];
    const float* b_ih1 = (const float*)d_in[6];
    const float* b_hh1 = (const float*)d_in[7];
    const float* w_ih2 = (const float*)d_in[8];
    const float* w_hh2 = (const float*)d_in[9];
    const float* b_ih2 = (const float*)d_in[10];
    const float* b_hh2 = (const float*)d_in[11];

    unsigned int* cnt = (unsigned int*)d_ws;
    float* gh2 = (float*)((char*)d_ws + 256);   // keep off the counter cacheline

    hipMemsetAsync(d_ws, 0, 8, stream);         // reset counters every launch
    gru_fused<<<NBLK, 256, 0, stream>>>(ids, h1_in, h2_in, emb,
                                        w_ih1, w_hh1, b_ih1, b_hh1,
                                        w_ih2, w_hh2, b_ih2, b_hh2,
                                        (float*)d_out, cnt, gh2);
}

// Round 3
// 13.385 us; speedup vs baseline: 15.2168x; 15.2168x over previous
//
#include <hip/hip_runtime.h>
#include <math.h>

#define H1 1024
#define H2 512

__device__ __forceinline__ float sigmoidf_(float x) { return 1.0f / (1.0f + __expf(-x)); }
__device__ __forceinline__ float dot4(float4 a, float4 b) {
    return a.x * b.x + a.y * b.y + a.z * b.z + a.w * b.w;
}
__device__ __forceinline__ float wave_sum(float v) {
#pragma unroll
    for (int o = 32; o; o >>= 1) v += __shfl_xor(v, o, 64);
    return v;
}

// Kernel 1: 1024 wave-jobs, one per h1 element. 256 blocks x 4 waves.
// Each wave: 6 dots of length 1024 (3 vs emb row, 3 vs h1_in).
__global__ __launch_bounds__(256) void gru_k1(
    const int* __restrict__ ids,
    const float* __restrict__ h1_in,
    const float* __restrict__ emb,
    const float* __restrict__ w_ih1,
    const float* __restrict__ w_hh1,
    const float* __restrict__ b_ih1,
    const float* __restrict__ b_hh1,
    float* __restrict__ d_out)
{
    const int lane = threadIdx.x & 63;
    const int j = blockIdx.x * 4 + (threadIdx.x >> 6);   // [0, 1024)
    const float* xrow = emb + (size_t)ids[0] * H1;

    float acc[6] = {0, 0, 0, 0, 0, 0};
#pragma unroll
    for (int k = 0; k < 4; ++k) {
        const int idx = lane + 64 * k;                   // 256 float4 = 1024 floats
        const float4 x4 = ((const float4*)xrow)[idx];
        const float4 h4 = ((const float4*)h1_in)[idx];
#pragma unroll
        for (int g = 0; g < 3; ++g) {
            const float4 a = ((const float4*)(w_ih1 + (size_t)(g * H1 + j) * H1))[idx];
            const float4 c = ((const float4*)(w_hh1 + (size_t)(g * H1 + j) * H1))[idx];
            acc[g]     += dot4(x4, a);
            acc[3 + g] += dot4(h4, c);
        }
    }
#pragma unroll
    for (int g = 0; g < 6; ++g) acc[g] = wave_sum(acc[g]);
    if (lane == 0) {
        const float xr = acc[0] + b_ih1[j];
        const float xz = acc[1] + b_ih1[j + H1];
        const float xn = acc[2] + b_ih1[j + 2 * H1];
        const float hr = acc[3] + b_hh1[j];
        const float hz = acc[4] + b_hh1[j + H1];
        const float hn = acc[5] + b_hh1[j + 2 * H1];
        const float r = sigmoidf_(xr + hr);
        const float z = sigmoidf_(xz + hz);
        const float n = tanhf(xn + r * hn);
        d_out[H2 + j] = (1.0f - z) * n + z * h1_in[j];   // h1 at flat offset 512
    }
}

// Kernel 2: 512 wave-jobs, one per h2 element. 128 blocks x 4 waves.
// Each wave: 3 dots of length 1024 (vs h1, read from d_out) and
//            3 dots of length 512 (vs h2_in). No workspace needed.
__global__ __launch_bounds__(256) void gru_k2(
    const float* __restrict__ h2_in,
    const float* __restrict__ w_ih2,
    const float* __restrict__ w_hh2,
    const float* __restrict__ b_ih2,
    const float* __restrict__ b_hh2,
    float* __restrict__ d_out)
{
    const int lane = threadIdx.x & 63;
    const int j = blockIdx.x * 4 + (threadIdx.x >> 6);   // [0, 512)
    const float* h1v = d_out + H2;                       // written by gru_k1

    float accx[3] = {0, 0, 0};
#pragma unroll
    for (int k = 0; k < 4; ++k) {
        const int idx = lane + 64 * k;                   // 256 float4 = 1024 floats
        const float4 hh = ((const float4*)h1v)[idx];
#pragma unroll
        for (int g = 0; g < 3; ++g) {
            const float4 a = ((const float4*)(w_ih2 + (size_t)(g * H2 + j) * H1))[idx];
            accx[g] += dot4(hh, a);
        }
    }
    float acch[3] = {0, 0, 0};
#pragma unroll
    for (int k = 0; k < 2; ++k) {
        const int idx = lane + 64 * k;                   // 128 float4 = 512 floats
        const float4 h4 = ((const float4*)h2_in)[idx];
#pragma unroll
        for (int g = 0; g < 3; ++g) {
            const float4 c = ((const float4*)(w_hh2 + (size_t)(g * H2 + j) * H2))[idx];
            acch[g] += dot4(h4, c);
        }
    }
#pragma unroll
    for (int g = 0; g < 3; ++g) { accx[g] = wave_sum(accx[g]); acch[g] = wave_sum(acch[g]); }
    if (lane == 0) {
        const float xr = accx[0] + b_ih2[j];
        const float xz = accx[1] + b_ih2[j + H2];
        const float xn = accx[2] + b_ih2[j + 2 * H2];
        const float hr = acch[0] + b_hh2[j];
        const float hz = acch[1] + b_hh2[j + H2];
        const float hn = acch[2] + b_hh2[j + 2 * H2];
        const float r = sigmoidf_(xr + hr);
        const float z = sigmoidf_(xz + hz);
        const float n = tanhf(xn + r * hn);
        const float h = (1.0f - z) * n + z * h2_in[j];
        d_out[j] = h;                // output (== h2)
        d_out[3 * H2 + j] = h;       // h2 at flat offset 1536
    }
}

extern "C" void kernel_launch(void* const* d_in, const int* in_sizes, int n_in,
                              void* d_out, int out_size, void* d_ws, size_t ws_size,
                              hipStream_t stream) {
    const int*   ids   = (const int*)d_in[0];
    const float* h1_in = (const float*)d_in[1];
    const float* h2_in = (const float*)d_in[2];
    const float* emb   = (const float*)d_in[3];
    const float* w_ih1 = (const float*)d_in[4];
    const float* w_hh1 = (const float*)d_in[5];
    const float* b_ih1 = (const float*)d_in[6];
    const float* b_hh1 = (const float*)d_in[7];
    const float* w_ih2 = (const float*)d_in[8];
    const float* w_hh2 = (const float*)d_in[9];
    const float* b_ih2 = (const float*)d_in[10];
    const float* b_hh2 = (const float*)d_in[11];
    float* out = (float*)d_out;

    gru_k1<<<H1 / 4, 256, 0, stream>>>(ids, h1_in, emb, w_ih1, w_hh1, b_ih1, b_hh1, out);
    gru_k2<<<H2 / 4, 256, 0, stream>>>(h2_in, w_ih2, w_hh2, b_ih2, b_hh2, out);
}